// Round 4
// baseline (416.194 us; speedup 1.0000x reference)
//
#include <hip/hip_runtime.h>
#include <math.h>

// ---------------------------------------------------------------------------
// Shapes: 5 streams x B=2 x N=1024 x C=768; H=12 heads x D=64; AD=8; HID=3072
// TOK = 5*2*1024 = 10240 rows everywhere.
// ---------------------------------------------------------------------------
typedef __bf16 bf16;
typedef __attribute__((ext_vector_type(8))) __bf16 bf16x8;
typedef __attribute__((ext_vector_type(4))) __bf16 bf16x4;
typedef __attribute__((ext_vector_type(4))) float f32x4;
typedef __attribute__((ext_vector_type(16))) float f32x16;

#define TOK   10240
#define CD    768
#define NQKV  2304
#define NHID  3072
#define SEQ   1024
#define NH    12

__device__ __forceinline__ f32x4 mfma16(bf16x8 a, bf16x8 b, f32x4 c) {
  return __builtin_amdgcn_mfma_f32_16x16x32_bf16(a, b, c, 0, 0, 0);
}
__device__ __forceinline__ f32x16 mfma32(bf16x8 a, bf16x8 b, f32x16 c) {
  return __builtin_amdgcn_mfma_f32_32x32x16_bf16(a, b, c, 0, 0, 0);
}

// async global->LDS, 16B per lane. LDS dest must be wave-uniform base;
// HW writes at base + lane*16. Global src is per-lane.
__device__ __forceinline__ void gload16(const void* g, void* l) {
  __builtin_amdgcn_global_load_lds(
      (const __attribute__((address_space(1))) void*)g,
      (__attribute__((address_space(3))) void*)l, 16, 0, 0);
}

__device__ __forceinline__ unsigned pack2(bf16 a, bf16 b) {
  union { unsigned short u[2]; unsigned v; } x;
  x.u[0] = __builtin_bit_cast(unsigned short, a);
  x.u[1] = __builtin_bit_cast(unsigned short, b);
  return x.v;
}

// tanh-approx GELU (abs err ~3e-3, fine vs 0.11 threshold); __expf is HW exp
__device__ __forceinline__ float fast_gelu(float v) {
  float u = 0.7978845608f * (v + 0.044715f * v * v * v);
  float e = __expf(fminf(2.f * u, 30.f));
  return 0.5f * v * (1.f + (e - 1.f) / (e + 1.f));
}

// ---------------------------------------------------------------------------
// Weight convert+transpose: in [K][N] f32 -> out [N][K] bf16
// ---------------------------------------------------------------------------
__global__ __launch_bounds__(256) void transpose_to_bf16(
    const float* __restrict__ in, bf16* __restrict__ out, int K, int N) {
  __shared__ float tile[32][33];
  const int bn = blockIdx.x * 32, bk = blockIdx.y * 32;
  const int r = threadIdx.x >> 5, c = threadIdx.x & 31;
#pragma unroll
  for (int i = 0; i < 4; ++i)
    tile[r + 8 * i][c] = in[(size_t)(bk + r + 8 * i) * N + bn + c];
  __syncthreads();
#pragma unroll
  for (int i = 0; i < 4; ++i)
    out[(size_t)(bn + r + 8 * i) * K + bk + c] = (bf16)tile[c][r + 8 * i];
}

// ---------------------------------------------------------------------------
// LN over 5 stacked stream inputs -> bf16 [TOK][768]
// ---------------------------------------------------------------------------
__global__ __launch_bounds__(256) void ln5_kernel(
    const float* __restrict__ x0, const float* __restrict__ x1,
    const float* __restrict__ x2, const float* __restrict__ x3,
    const float* __restrict__ x4, const float* __restrict__ g,
    const float* __restrict__ b, bf16* __restrict__ out) {
  const int w = threadIdx.x >> 6, lane = threadIdx.x & 63;
  const int row = blockIdx.x * 4 + w;
  const int s = row >> 11, rem = row & 2047;
  const float* xp;
  switch (s) {
    case 0: xp = x0; break; case 1: xp = x1; break; case 2: xp = x2; break;
    case 3: xp = x3; break; default: xp = x4; break;
  }
  const f32x4* xr = (const f32x4*)(xp + (size_t)rem * CD);
  f32x4 v[3];
#pragma unroll
  for (int i = 0; i < 3; ++i) v[i] = xr[lane + 64 * i];
  float sum = 0.f;
#pragma unroll
  for (int i = 0; i < 3; ++i)
#pragma unroll
    for (int j = 0; j < 4; ++j) sum += v[i][j];
#pragma unroll
  for (int m = 32; m >= 1; m >>= 1) sum += __shfl_xor(sum, m);
  const float mu = sum * (1.f / 768.f);
  float vs = 0.f;
#pragma unroll
  for (int i = 0; i < 3; ++i)
#pragma unroll
    for (int j = 0; j < 4; ++j) { float d = v[i][j] - mu; vs += d * d; }
#pragma unroll
  for (int m = 32; m >= 1; m >>= 1) vs += __shfl_xor(vs, m);
  const float rstd = rsqrtf(vs * (1.f / 768.f) + 1e-5f);
  const f32x4* gp = (const f32x4*)g;
  const f32x4* bp = (const f32x4*)b;
  bf16* orow = out + (size_t)row * CD;
#pragma unroll
  for (int i = 0; i < 3; ++i) {
    const int c4 = lane + 64 * i;
    f32x4 gg = gp[c4], bb = bp[c4];
    bf16x4 o;
#pragma unroll
    for (int j = 0; j < 4; ++j)
      o[j] = (bf16)((v[i][j] - mu) * rstd * gg[j] + bb[j]);
    *(bf16x4*)(orow + c4 * 4) = o;
  }
}

// ---------------------------------------------------------------------------
// FUSED: ys = xs + ao + cross(a1); write ys (f32) + ln1(ys),ln2(ys) (bf16)
// ---------------------------------------------------------------------------
__global__ __launch_bounds__(256) void fuse_res_ln(
    const float* __restrict__ x0, const float* __restrict__ x1,
    const float* __restrict__ x2, const float* __restrict__ x3,
    const float* __restrict__ x4, const float* __restrict__ add,
    const float* __restrict__ a, float* __restrict__ ys,
    const float* __restrict__ g1, const float* __restrict__ b1,
    const float* __restrict__ g2, const float* __restrict__ b2,
    bf16* __restrict__ o1, bf16* __restrict__ o2) {
  const int w = threadIdx.x >> 6, lane = threadIdx.x & 63;
  const int row = blockIdx.x * 4 + w;
  const int s = row >> 11, rem = row & 2047;
  const float* xp;
  switch (s) {
    case 0: xp = x0; break; case 1: xp = x1; break; case 2: xp = x2; break;
    case 3: xp = x3; break; default: xp = x4; break;
  }
  const f32x4* xr = (const f32x4*)(xp + (size_t)rem * CD);
  const f32x4* ar = (const f32x4*)(add + (size_t)row * CD);
  const f32x4* am = (const f32x4*)(a + (size_t)(row - 2048) * CD);
  const f32x4* ap = (const f32x4*)(a + (size_t)(row + 2048) * CD);
  f32x4 v[3];
#pragma unroll
  for (int i = 0; i < 3; ++i) {
    const int c4 = lane + 64 * i;
    f32x4 t = xr[c4] + ar[c4];
    if (s > 0) t += am[c4];
    if (s < 4) t += ap[c4];
    v[i] = t;
  }
  f32x4* yr = (f32x4*)(ys + (size_t)row * CD);
#pragma unroll
  for (int i = 0; i < 3; ++i) yr[lane + 64 * i] = v[i];

  float sum = 0.f;
#pragma unroll
  for (int i = 0; i < 3; ++i)
#pragma unroll
    for (int j = 0; j < 4; ++j) sum += v[i][j];
#pragma unroll
  for (int m = 32; m >= 1; m >>= 1) sum += __shfl_xor(sum, m);
  const float mu = sum * (1.f / 768.f);
  float vs = 0.f;
#pragma unroll
  for (int i = 0; i < 3; ++i)
#pragma unroll
    for (int j = 0; j < 4; ++j) { float d = v[i][j] - mu; vs += d * d; }
#pragma unroll
  for (int m = 32; m >= 1; m >>= 1) vs += __shfl_xor(vs, m);
  const float rstd = rsqrtf(vs * (1.f / 768.f) + 1e-5f);
  bf16* r1 = o1 + (size_t)row * CD;
  bf16* r2 = o2 + (size_t)row * CD;
#pragma unroll
  for (int i = 0; i < 3; ++i) {
    const int c4 = lane + 64 * i;
    f32x4 gg1 = ((const f32x4*)g1)[c4], bb1 = ((const f32x4*)b1)[c4];
    f32x4 gg2 = ((const f32x4*)g2)[c4], bb2 = ((const f32x4*)b2)[c4];
    bf16x4 oa, ob;
#pragma unroll
    for (int j = 0; j < 4; ++j) {
      float n = (v[i][j] - mu) * rstd;
      oa[j] = (bf16)(n * gg1[j] + bb1[j]);
      ob[j] = (bf16)(n * gg2[j] + bb2[j]);
    }
    *(bf16x4*)(r1 + c4 * 4) = oa;
    *(bf16x4*)(r2 + c4 * 4) = ob;
  }
}

// ---------------------------------------------------------------------------
// GEMM 256x256, BK=64, 8 waves (2M x 4N), 8-phase schedule (T2+T3+T4+T5).
// C[M,N] = A[M,K] @ Bt[N,K]^T + bias.
// LDS: As/Bs [2 dbuf][256 rows][64 k] bf16 = 128 KiB total, fully linear
// row-major; k-chunk (16B) XOR-swizzled by (row&7) on BOTH global source
// (pre-swizzle) and ds_read (rule #21).
// Per K-tile (4 phases): ph(mh,nh) in order (0,0),(0,1),(1,0),(1,1);
// A-frags loaded at nh==0 phases, B-frags (both nh) cached at ph1/ph2.
// One half-tile (128 rows, 2 gload16/thread) staged per phase; schedule is
// WAR-safe: each region restaged >=1 barrier-phase after its last ds_read.
// Counted vmcnt(4) at phases 4 and 8 gates the next tile (never 0 mid-loop).
// EPI: 0 = f32 store, 1 = bf16 store, 2 = fast-GELU -> bf16 store
// ---------------------------------------------------------------------------
#define GBAR() __builtin_amdgcn_s_barrier()

#define LOADA(MH, BUF)                                                      \
  _Pragma("unroll") for (int m_ = 0; m_ < 4; ++m_) {                        \
    af[m_][0] =                                                             \
        *(const bf16x8*)&As[BUF][((MH)*128 + arow + m_ * 16) * 64 + ach0];  \
    af[m_][1] =                                                             \
        *(const bf16x8*)&As[BUF][((MH)*128 + arow + m_ * 16) * 64 + ach1];  \
  }

#define LOADB(DST, NH, BUF)                                                 \
  _Pragma("unroll") for (int n_ = 0; n_ < 2; ++n_) {                        \
    DST[n_][0] =                                                            \
        *(const bf16x8*)&Bs[BUF][(brow + (NH)*32 + n_ * 16) * 64 + ach0];   \
    DST[n_][1] =                                                            \
        *(const bf16x8*)&Bs[BUF][(brow + (NH)*32 + n_ * 16) * 64 + ach1];   \
  }

#define MFMA_PH(MH, NH, BF)                                                 \
  __builtin_amdgcn_s_setprio(1);                                            \
  _Pragma("unroll") for (int m_ = 0; m_ < 4; ++m_)                          \
  _Pragma("unroll") for (int n_ = 0; n_ < 2; ++n_) {                        \
    acc[(MH)*4 + m_][(NH)*2 + n_] =                                         \
        mfma16(af[m_][0], BF[n_][0], acc[(MH)*4 + m_][(NH)*2 + n_]);        \
    acc[(MH)*4 + m_][(NH)*2 + n_] =                                         \
        mfma16(af[m_][1], BF[n_][1], acc[(MH)*4 + m_][(NH)*2 + n_]);        \
  }                                                                         \
  __builtin_amdgcn_s_setprio(0);

template <int EPI>
__global__ __launch_bounds__(512, 2) void gemm256(
    const bf16* __restrict__ A, const bf16* __restrict__ Bt,
    const float* __restrict__ bias, void* __restrict__ Cout, int N, int K,
    int nbn) {
  __shared__ bf16 As[2][16384];
  __shared__ bf16 Bs[2][16384];
  const int t = threadIdx.x, lane = t & 63, w = t >> 6;
  const int wm = w >> 2, wn = w & 3;

  // bijective XCD-chunked remap (gridDim.x % 8 == 0 by construction)
  const int chunkg = gridDim.x >> 3;
  const int wg = (blockIdx.x & 7) * chunkg + (blockIdx.x >> 3);
  const int bm = wg / nbn, bn = wg % nbn;

  f32x4 acc[8][4] = {};

  // staging: half-tile = 128 rows x 64k (16KB); 2 gload16 per thread.
  // thread covers LDS slot (row = t>>3 [+64 issue1], chunk = t&7);
  // source pre-swizzle: global chunk = (t&7) ^ (row&7).
  const int srow = t >> 3;
  const int scol = ((t & 7) ^ (srow & 7)) << 3;
  const bf16* Ab = A + (size_t)(bm * 256 + srow) * K + scol;
  const bf16* Bb = Bt + (size_t)(bn * 256 + srow) * K + scol;
  const size_t r64 = (size_t)64 * K;

  auto stage_a = [&](int buf, int h, int kt) {
    const bf16* g = Ab + (size_t)h * 128 * K + (size_t)kt * 64;
    gload16(g, &As[buf][h * 8192 + w * 512]);
    gload16(g + r64, &As[buf][h * 8192 + 4096 + w * 512]);
  };
  auto stage_b = [&](int buf, int h, int kt) {
    const bf16* g = Bb + (size_t)h * 128 * K + (size_t)kt * 64;
    gload16(g, &Bs[buf][h * 8192 + w * 512]);
    gload16(g + r64, &Bs[buf][h * 8192 + 4096 + w * 512]);
  };

  // fragment read constants: row&7 == lane&7 for every frag row
  const int arow = wm * 64 + (lane & 15);
  const int brow = wn * 64 + (lane & 15);
  const int ach0 = (((lane >> 4) + 0) ^ (lane & 7)) << 3;
  const int ach1 = (((lane >> 4) + 4) ^ (lane & 7)) << 3;

  // prologue: T0 {A0,B0,B1,A1}, T1 {A0,B0}  (12 vmcnt events)
  stage_a(0, 0, 0); stage_b(0, 0, 0); stage_b(0, 1, 0); stage_a(0, 1, 0);
  stage_a(1, 0, 1); stage_b(1, 0, 1);
  asm volatile("s_waitcnt vmcnt(4)" ::: "memory");  // T0 landed
  GBAR();

  const int NT = K >> 6, NI = NT >> 1;
  bf16x8 af[4][2], bf0[2][2], bf1[2][2];

  for (int j = 0; j < NI; ++j) {
    const int tA = 2 * j, tB = 2 * j + 1;
    const bool notlast = (j + 1 < NI);

    // ======== tile tA from buf 0 ========
    // ph1 (0,0): read A-h0 + both B halves' nh0 frags; stage tB.B1
    LOADA(0, 0);
    LOADB(bf0, 0, 0);
    stage_b(1, 1, tB);
    GBAR();
    MFMA_PH(0, 0, bf0);
    GBAR();
    // ph2 (0,1): read B nh1 frags; stage tB.A1
    LOADB(bf1, 1, 0);
    stage_a(1, 1, tB);
    GBAR();
    MFMA_PH(0, 1, bf1);
    GBAR();
    // ph3 (1,0): read A-h1; stage (tA+2).A0 (A-h0 last read ph1)
    LOADA(1, 0);
    if (notlast) stage_a(0, 0, tA + 2);
    GBAR();
    MFMA_PH(1, 0, bf0);
    GBAR();
    // ph4 (1,1): stage (tA+2).B0 (B last read ph2); gate tile tB
    if (notlast) {
      stage_b(0, 0, tA + 2);
      asm volatile("s_waitcnt vmcnt(4)" ::: "memory");
    } else {
      asm volatile("s_waitcnt vmcnt(0)" ::: "memory");
    }
    GBAR();
    MFMA_PH(1, 1, bf1);
    GBAR();

    // ======== tile tB from buf 1 ========
    // ph5 (0,0): stage (tA+2).B1
    LOADA(0, 1);
    LOADB(bf0, 0, 1);
    if (notlast) stage_b(0, 1, tA + 2);
    GBAR();
    MFMA_PH(0, 0, bf0);
    GBAR();
    // ph6 (0,1): stage (tA+2).A1 (A-h1 of buf0 last read ph3/4)
    LOADB(bf1, 1, 1);
    if (notlast) stage_a(0, 1, tA + 2);
    GBAR();
    MFMA_PH(0, 1, bf1);
    GBAR();
    // ph7 (1,0): stage (tB+2).A0 (buf1 A-h0 last read ph5)
    LOADA(1, 1);
    if (notlast) stage_a(1, 0, tB + 2);
    GBAR();
    MFMA_PH(1, 0, bf0);
    GBAR();
    // ph8 (1,1): stage (tB+2).B0; gate tile tA+2
    if (notlast) {
      stage_b(1, 0, tB + 2);
      asm volatile("s_waitcnt vmcnt(4)" ::: "memory");
    }
    GBAR();
    MFMA_PH(1, 1, bf1);
    GBAR();
  }

  // epilogue
#pragma unroll
  for (int am = 0; am < 8; ++am) {
    const int grow0 =
        bm * 256 + (am >> 2) * 128 + wm * 64 + (am & 3) * 16 + (lane >> 4) * 4;
#pragma unroll
    for (int an = 0; an < 4; ++an) {
      const int gcol = bn * 256 + wn * 64 + an * 16 + (lane & 15);
      const float bv = bias[gcol];
#pragma unroll
      for (int r = 0; r < 4; ++r) {
        float v = acc[am][an][r] + bv;
        if (EPI == 2) v = fast_gelu(v);
        const size_t idx = (size_t)(grow0 + r) * N + gcol;
        if (EPI == 0) ((float*)Cout)[idx] = v;
        else ((bf16*)Cout)[idx] = (bf16)v;
      }
    }
  }
}

// ---------------------------------------------------------------------------
// Flash attention v2 — swapped-operand 32x32 MFMA, in-register softmax.
// ---------------------------------------------------------------------------
__global__ __launch_bounds__(256, 3) void attn_v2(
    const bf16* __restrict__ qkv, bf16* __restrict__ obuf) {
  __shared__ bf16 Ks[2][4096];
  __shared__ bf16 Vt[2][4096];
  const int t = threadIdx.x, lane = t & 63, w = t >> 6;
  const int g = lane >> 5, q32 = lane & 31, rq7 = q32 & 7;

  const int xcd = blockIdx.x & 7, slot = blockIdx.x >> 3;
  const int work = xcd * 120 + slot;
  const int sbh = work >> 3, qt = work & 7;
  const int sb = sbh / NH, h = sbh % NH;
  const size_t tokbase = (size_t)sb * SEQ;
  const int qoff = h * 64, koff = CD + h * 64, voff = 2 * CD + h * 64;

  const int qrow = qt * 128 + w * 32 + q32;
  bf16x8 qf[4];
  {
    const bf16* qp = qkv + (tokbase + qrow) * NQKV + qoff + g * 8;
#pragma unroll
    for (int kd = 0; kd < 4; ++kd) {
      bf16x8 v = *(const bf16x8*)(qp + kd * 16);
#pragma unroll
      for (int j = 0; j < 8; ++j) v[j] = (bf16)((float)v[j] * 0.125f);
      qf[kd] = v;
    }
  }

  const int skv1 = t >> 3, sc1 = (t & 7) ^ (skv1 & 7);
  const int skv2 = (t + 256) >> 3, sc2 = (t & 7) ^ (skv2 & 7);
  const int vkv0 = 2 * (t & 31);
  const int vd0 = 8 * (t >> 5);
  const int c0 = (vkv0 & 51) | ((vkv0 & 4) << 1) | ((vkv0 & 8) >> 1);
  const int vchunk = c0 >> 3, vsub = c0 & 7;
  const bf16* kbase = qkv + tokbase * NQKV + koff;
  const bf16* vbase = qkv + tokbase * NQKV + voff;

  {
    const bf16* kb0 = kbase;
    gload16(kb0 + (size_t)skv1 * NQKV + sc1 * 8, &Ks[0][w * 512]);
    gload16(kb0 + (size_t)skv2 * NQKV + sc2 * 8, &Ks[0][2048 + w * 512]);
    const bf16* vp = vbase + (size_t)vkv0 * NQKV + vd0;
    bf16x8 r0 = *(const bf16x8*)vp;
    bf16x8 r1 = *(const bf16x8*)(vp + NQKV);
#pragma unroll
    for (int j = 0; j < 8; ++j) {
      const int d = vd0 + j;
      *(unsigned*)&Vt[0][d * 64 + ((vchunk ^ j) << 3) + vsub] =
          pack2(r0[j], r1[j]);
    }
  }
  __syncthreads();

  float m_run = -1e30f, l_run = 0.f;
  f32x16 oT0 = {}, oT1 = {};
  int cur = 0;

  for (int kt = 0; kt < 16; ++kt) {
    bf16x8 nv0, nv1;
    if (kt < 15) {
      const bf16* vp = vbase + (size_t)((kt + 1) * 64 + vkv0) * NQKV + vd0;
      nv0 = *(const bf16x8*)vp;
      nv1 = *(const bf16x8*)(vp + NQKV);
      const bf16* kb0 = kbase + (size_t)(kt + 1) * 64 * NQKV;
      gload16(kb0 + (size_t)skv1 * NQKV + sc1 * 8, &Ks[cur ^ 1][w * 512]);
      gload16(kb0 + (size_t)skv2 * NQKV + sc2 * 8,
              &Ks[cur ^ 1][2048 + w * 512]);
    }

    f32x16 sT0 = {}, sT1 = {};
#pragma unroll
    for (int kd = 0; kd < 4; ++kd) {
      bf16x8 kf0 =
          *(const bf16x8*)&Ks[cur][q32 * 64 + (((2 * kd + g) ^ rq7) << 3)];
      bf16x8 kf1 = *(const bf16x8*)&Ks[cur][(32 + q32) * 64 +
                                            (((2 * kd + g) ^ rq7) << 3)];
      sT0 = mfma32(kf0, qf[kd], sT0);
      sT1 = mfma32(kf1, qf[kd], sT1);
    }

    float mt = sT0[0];
#pragma unroll
    for (int r = 1; r < 16; ++r) mt = fmaxf(mt, sT0[r]);
#pragma unroll
    for (int r = 0; r < 16; ++r) mt = fmaxf(mt, sT1[r]);
    mt = fmaxf(mt, __shfl_xor(mt, 32));
    const float mnew = fmaxf(m_run, mt);
    const float alpha = __expf(m_run - mnew);
    m_run = mnew;
    float rs = 0.f;
#pragma unroll
    for (int r = 0; r < 16; ++r) {
      sT0[r] = __expf(sT0[r] - mnew);
      rs += sT0[r];
    }
#pragma unroll
    for (int r = 0; r < 16; ++r) {
      sT1[r] = __expf(sT1[r] - mnew);
      rs += sT1[r];
    }
    rs += __shfl_xor(rs, 32);
    l_run = l_run * alpha + rs;
#pragma unroll
    for (int r = 0; r < 16; ++r) { oT0[r] *= alpha; oT1[r] *= alpha; }

    bf16x8 pa[4];
#pragma unroll
    for (int hh = 0; hh < 2; ++hh)
#pragma unroll
      for (int j = 0; j < 8; ++j) {
        pa[hh][j] = (bf16)sT0[8 * hh + j];
        pa[2 + hh][j] = (bf16)sT1[8 * hh + j];
      }

#pragma unroll
    for (int ks = 0; ks < 4; ++ks) {
      bf16x8 vf0 =
          *(const bf16x8*)&Vt[cur][q32 * 64 + (((2 * ks + g) ^ rq7) << 3)];
      bf16x8 vf1 = *(const bf16x8*)&Vt[cur][(32 + q32) * 64 +
                                            (((2 * ks + g) ^ rq7) << 3)];
      oT0 = mfma32(vf0, pa[ks], oT0);
      oT1 = mfma32(vf1, pa[ks], oT1);
    }

    if (kt < 15) {
#pragma unroll
      for (int j = 0; j < 8; ++j) {
        const int d = vd0 + j;
        *(unsigned*)&Vt[cur ^ 1][d * 64 + ((vchunk ^ j) << 3) + vsub] =
            pack2(nv0[j], nv1[j]);
      }
    }
    __syncthreads();
    cur ^= 1;
  }

  const float rl = 1.f / l_run;
  bf16* orow = obuf + (tokbase + qrow) * CD + h * 64;
#pragma unroll
  for (int m = 0; m < 4; ++m) {
    bf16x4 o0, o1;
#pragma unroll
    for (int r = 0; r < 4; ++r) {
      o0[r] = (bf16)(oT0[4 * m + r] * rl);
      o1[r] = (bf16)(oT1[4 * m + r] * rl);
    }
    *(bf16x4*)(orow + 8 * m + 4 * g) = o0;
    *(bf16x4*)(orow + 32 + 8 * m + 4 * g) = o1;
  }
}

// ---------------------------------------------------------------------------
// Adapter: out = ((X@dw+db)@mw+mb)@uw+ub ; X bf16 [TOK][768], out f32.
// ---------------------------------------------------------------------------
__global__ __launch_bounds__(256) void adapter_kernel(
    const bf16* __restrict__ X, const float* __restrict__ dw,
    const float* __restrict__ db, const float* __restrict__ mw,
    const float* __restrict__ mb, const float* __restrict__ uw,
    const float* __restrict__ ub, float* __restrict__ out) {
  const int tok = blockIdx.x * 4 + (threadIdx.x >> 6);
  const int lane = threadIdx.x & 63;
  const bf16* xr = X + (size_t)tok * CD;
  float xv[12];
#pragma unroll
  for (int i = 0; i < 12; ++i) xv[i] = (float)xr[lane + 64 * i];
  float h1[8] = {0, 0, 0, 0, 0, 0, 0, 0};
#pragma unroll
  for (int i = 0; i < 12; ++i) {
    const f32x4* dr = (const f32x4*)(dw + (size_t)(lane + 64 * i) * 8);
    f32x4 d0 = dr[0], d1 = dr[1];
#pragma unroll
    for (int j = 0; j < 4; ++j) {
      h1[j] += xv[i] * d0[j];
      h1[4 + j] += xv[i] * d1[j];
    }
  }
#pragma unroll
  for (int m = 1; m < 64; m <<= 1)
#pragma unroll
    for (int j = 0; j < 8; ++j) h1[j] += __shfl_xor(h1[j], m);
#pragma unroll
  for (int j = 0; j < 8; ++j) h1[j] += db[j];
  float h2[8];
#pragma unroll
  for (int k = 0; k < 8; ++k) {
    float v = mb[k];
#pragma unroll
    for (int j = 0; j < 8; ++j) v += h1[j] * mw[j * 8 + k];
    h2[k] = v;
  }
#pragma unroll
  for (int i = 0; i < 12; ++i) {
    const int c = lane + 64 * i;
    float v = ub[c];
#pragma unroll
    for (int k = 0; k < 8; ++k) v += h2[k] * uw[k * CD + c];
    out[(size_t)tok * CD + c] = v;
  }
}

// ---------------------------------------------------------------------------
// out[s] = p_s + add[s] + (s>0 ? a[s-1] : 0) + (s<4 ? a[s+1] : 0)
// ---------------------------------------------------------------------------
__global__ __launch_bounds__(256) void cross_residual(
    const float* __restrict__ p0, const float* __restrict__ p1,
    const float* __restrict__ p2, const float* __restrict__ p3,
    const float* __restrict__ p4, const float* __restrict__ add,
    const float* __restrict__ a, float* __restrict__ out) {
  const int s = blockIdx.y;
  const size_t i = (size_t)blockIdx.x * 256 + threadIdx.x;  // f32x4 index
  const size_t spitch = (size_t)2048 * 768 / 4;
  const size_t sb = (size_t)s * spitch;
  const float* p;
  switch (s) {
    case 0: p = p0; break; case 1: p = p1; break; case 2: p = p2; break;
    case 3: p = p3; break; default: p = p4; break;
  }
  f32x4 v = ((const f32x4*)p)[i];
  v += ((const f32x4*)add)[sb + i];
  if (s > 0) v += ((const f32x4*)a)[sb - spitch + i];
  if (s < 4) v += ((const f32x4*)a)[sb + spitch + i];
  ((f32x4*)out)[sb + i] = v;
}

// ---------------------------------------------------------------------------
// workspace layout (bytes; needs ~203 MB)
// ---------------------------------------------------------------------------
#define OFF_WTQKV  ((size_t)0)           // bf16 [2304][768]
#define OFF_WTPROJ ((size_t)3538944)     // bf16 [768][768]
#define OFF_WTFC1  ((size_t)4718592)     // bf16 [3072][768]
#define OFF_WTFC2  ((size_t)9437184)     // bf16 [768][3072]
#define OFF_N1     ((size_t)14155776)    // bf16 [10240][768]; later ln1(ys)
#define OFF_BIG    ((size_t)29884416)    // bf16 qkv [10240][2304]; later h [10240][3072]
#define OFF_OBUF   ((size_t)77070336)    // bf16 o [10240][768] (tail of BIG)
#define OFF_AOM    ((size_t)92798976)    // f32 [10240][768]: ao, later m
#define OFF_A12    ((size_t)124256256)   // f32 [10240][768]: a1, later a2
#define OFF_YS     ((size_t)155713536)   // f32 [10240][768]
#define OFF_L2Y    ((size_t)187170816)   // bf16 [10240][768]

extern "C" void kernel_launch(void* const* d_in, const int* in_sizes, int n_in,
                              void* d_out, int out_size, void* d_ws,
                              size_t ws_size, hipStream_t stream) {
  const float* x0 = (const float*)d_in[0];
  const float* x1 = (const float*)d_in[1];
  const float* x2 = (const float*)d_in[2];
  const float* x3 = (const float*)d_in[3];
  const float* x4 = (const float*)d_in[4];
  const float* ln1_g = (const float*)d_in[5];
  const float* ln1_b = (const float*)d_in[6];
  const float* ln2_g = (const float*)d_in[7];
  const float* ln2_b = (const float*)d_in[8];
  const float* qkv_w = (const float*)d_in[9];
  const float* qkv_b = (const float*)d_in[10];
  const float* proj_w = (const float*)d_in[11];
  const float* proj_b = (const float*)d_in[12];
  const float* fc1_w = (const float*)d_in[13];
  const float* fc1_b = (const float*)d_in[14];
  const float* fc2_w = (const float*)d_in[15];
  const float* fc2_b = (const float*)d_in[16];
  const float* at_dw = (const float*)d_in[17];
  const float* at_db = (const float*)d_in[18];
  const float* at_mw = (const float*)d_in[19];
  const float* at_mb = (const float*)d_in[20];
  const float* at_uw = (const float*)d_in[21];
  const float* at_ub = (const float*)d_in[22];
  const float* a2_dw = (const float*)d_in[23];
  const float* a2_db = (const float*)d_in[24];
  const float* a2_mw = (const float*)d_in[25];
  const float* a2_mb = (const float*)d_in[26];
  const float* a2_uw = (const float*)d_in[27];
  const float* a2_ub = (const float*)d_in[28];

  char* ws = (char*)d_ws;
  bf16* wt_qkv = (bf16*)(ws + OFF_WTQKV);
  bf16* wt_proj = (bf16*)(ws + OFF_WTPROJ);
  bf16* wt_fc1 = (bf16*)(ws + OFF_WTFC1);
  bf16* wt_fc2 = (bf16*)(ws + OFF_WTFC2);
  bf16* n1 = (bf16*)(ws + OFF_N1);
  bf16* qkvb = (bf16*)(ws + OFF_BIG);
  bf16* obuf = (bf16*)(ws + OFF_OBUF);
  float* aom = (float*)(ws + OFF_AOM);
  float* a12 = (float*)(ws + OFF_A12);
  float* ysb = (float*)(ws + OFF_YS);
  bf16* l2y = (bf16*)(ws + OFF_L2Y);

  const dim3 b256(256);
  const dim3 b512(512);

  // 1. weight convert+transpose -> bf16 [N][K]
  transpose_to_bf16<<<dim3(72, 24), b256, 0, stream>>>(qkv_w, wt_qkv, 768, 2304);
  transpose_to_bf16<<<dim3(24, 24), b256, 0, stream>>>(proj_w, wt_proj, 768, 768);
  transpose_to_bf16<<<dim3(96, 24), b256, 0, stream>>>(fc1_w, wt_fc1, 768, 3072);
  transpose_to_bf16<<<dim3(24, 96), b256, 0, stream>>>(fc2_w, wt_fc2, 3072, 768);

  // 2. n1 = LN(xs)  (bf16)
  ln5_kernel<<<2560, b256, 0, stream>>>(x0, x1, x2, x3, x4, ln1_g, ln1_b, n1);

  // 3. qkv = n1 @ qkv_w + qkv_b  (bf16)   grid 40*9=360 (%8==0)
  gemm256<1><<<360, b512, 0, stream>>>(n1, wt_qkv, qkv_b, qkvb, NQKV, 768, 9);

  // 4. a1 = adapter(n1)  (f32)
  adapter_kernel<<<2560, b256, 0, stream>>>(n1, at_dw, at_db, at_mw, at_mb,
                                            at_uw, at_ub, a12);

  // 5. attention -> o (bf16)
  attn_v2<<<960, b256, 0, stream>>>(qkvb, obuf);

  // 6. ao = o @ proj_w + proj_b  (f32)   grid 40*3=120
  gemm256<0><<<120, b512, 0, stream>>>(obuf, wt_proj, proj_b, aom, CD, 768, 3);

  // 7+8. ys = xs + ao + cross(a1); ln1(ys)->n1, ln2(ys)->l2y  (fused)
  fuse_res_ln<<<2560, b256, 0, stream>>>(x0, x1, x2, x3, x4, aom, a12, ysb,
                                         ln1_g, ln1_b, ln2_g, ln2_b, n1, l2y);

  // 9. a2 = adapter(ln1(ys))  (overwrites a1)
  adapter_kernel<<<2560, b256, 0, stream>>>(n1, a2_dw, a2_db, a2_mw, a2_mb,
                                            a2_uw, a2_ub, a12);

  // 10. h = gelu(ln2(ys) @ fc1_w + fc1_b)  (bf16)   grid 40*12=480
  gemm256<2><<<480, b512, 0, stream>>>(l2y, wt_fc1, fc1_b, qkvb, NHID, 768, 12);

  // 11. m = h @ fc2_w + fc2_b  (f32)   grid 40*3=120
  gemm256<0><<<120, b512, 0, stream>>>(qkvb, wt_fc2, fc2_b, aom, CD, NHID, 3);

  // 12. z = ys + m + cross(a2) -> d_out
  const size_t sp = (size_t)2048 * 768;
  cross_residual<<<dim3(1536, 5), b256, 0, stream>>>(
      ysb, ysb + sp, ysb + 2 * sp, ysb + 3 * sp, ysb + 4 * sp, aom, a12,
      (float*)d_out);
}

// Round 5
// 382.909 us; speedup vs baseline: 1.0869x; 1.0869x over previous
//
#include <hip/hip_runtime.h>
#include <math.h>

// ---------------------------------------------------------------------------
// Shapes: 5 streams x B=2 x N=1024 x C=768; H=12 heads x D=64; AD=8; HID=3072
// TOK = 5*2*1024 = 10240 rows everywhere.
// ---------------------------------------------------------------------------
typedef __bf16 bf16;
typedef __attribute__((ext_vector_type(8))) __bf16 bf16x8;
typedef __attribute__((ext_vector_type(4))) __bf16 bf16x4;
typedef __attribute__((ext_vector_type(4))) float f32x4;
typedef __attribute__((ext_vector_type(16))) float f32x16;

#define TOK   10240
#define CD    768
#define NQKV  2304
#define NHID  3072
#define SEQ   1024
#define NH    12

__device__ __forceinline__ f32x4 mfma16(bf16x8 a, bf16x8 b, f32x4 c) {
  return __builtin_amdgcn_mfma_f32_16x16x32_bf16(a, b, c, 0, 0, 0);
}
__device__ __forceinline__ f32x16 mfma32(bf16x8 a, bf16x8 b, f32x16 c) {
  return __builtin_amdgcn_mfma_f32_32x32x16_bf16(a, b, c, 0, 0, 0);
}

// async global->LDS, 16B per lane. LDS dest must be wave-uniform base;
// HW writes at base + lane*16. Global src is per-lane.
__device__ __forceinline__ void gload16(const void* g, void* l) {
  __builtin_amdgcn_global_load_lds(
      (const __attribute__((address_space(1))) void*)g,
      (__attribute__((address_space(3))) void*)l, 16, 0, 0);
}

__device__ __forceinline__ unsigned pack2(bf16 a, bf16 b) {
  union { unsigned short u[2]; unsigned v; } x;
  x.u[0] = __builtin_bit_cast(unsigned short, a);
  x.u[1] = __builtin_bit_cast(unsigned short, b);
  return x.v;
}

__device__ __forceinline__ f32x4 b4tof(const bf16* p) {
  bf16x4 v = *(const bf16x4*)p;
  f32x4 r;
#pragma unroll
  for (int j = 0; j < 4; ++j) r[j] = (float)v[j];
  return r;
}

// tanh-approx GELU (abs err ~3e-3, fine vs 0.11 threshold); __expf is HW exp
__device__ __forceinline__ float fast_gelu(float v) {
  float u = 0.7978845608f * (v + 0.044715f * v * v * v);
  float e = __expf(fminf(2.f * u, 30.f));
  return 0.5f * v * (1.f + (e - 1.f) / (e + 1.f));
}

// ---------------------------------------------------------------------------
// Weight convert+transpose: in [K][N] f32 -> out [N][K] bf16
// ---------------------------------------------------------------------------
__global__ __launch_bounds__(256) void transpose_to_bf16(
    const float* __restrict__ in, bf16* __restrict__ out, int K, int N) {
  __shared__ float tile[32][33];
  const int bn = blockIdx.x * 32, bk = blockIdx.y * 32;
  const int r = threadIdx.x >> 5, c = threadIdx.x & 31;
#pragma unroll
  for (int i = 0; i < 4; ++i)
    tile[r + 8 * i][c] = in[(size_t)(bk + r + 8 * i) * N + bn + c];
  __syncthreads();
#pragma unroll
  for (int i = 0; i < 4; ++i)
    out[(size_t)(bn + r + 8 * i) * K + bk + c] = (bf16)tile[c][r + 8 * i];
}

// ---------------------------------------------------------------------------
// LN over 5 stacked stream inputs -> bf16 [TOK][768]
// ---------------------------------------------------------------------------
__global__ __launch_bounds__(256) void ln5_kernel(
    const float* __restrict__ x0, const float* __restrict__ x1,
    const float* __restrict__ x2, const float* __restrict__ x3,
    const float* __restrict__ x4, const float* __restrict__ g,
    const float* __restrict__ b, bf16* __restrict__ out) {
  const int w = threadIdx.x >> 6, lane = threadIdx.x & 63;
  const int row = blockIdx.x * 4 + w;
  const int s = row >> 11, rem = row & 2047;
  const float* xp;
  switch (s) {
    case 0: xp = x0; break; case 1: xp = x1; break; case 2: xp = x2; break;
    case 3: xp = x3; break; default: xp = x4; break;
  }
  const f32x4* xr = (const f32x4*)(xp + (size_t)rem * CD);
  f32x4 v[3];
#pragma unroll
  for (int i = 0; i < 3; ++i) v[i] = xr[lane + 64 * i];
  float sum = 0.f;
#pragma unroll
  for (int i = 0; i < 3; ++i)
#pragma unroll
    for (int j = 0; j < 4; ++j) sum += v[i][j];
#pragma unroll
  for (int m = 32; m >= 1; m >>= 1) sum += __shfl_xor(sum, m);
  const float mu = sum * (1.f / 768.f);
  float vs = 0.f;
#pragma unroll
  for (int i = 0; i < 3; ++i)
#pragma unroll
    for (int j = 0; j < 4; ++j) { float d = v[i][j] - mu; vs += d * d; }
#pragma unroll
  for (int m = 32; m >= 1; m >>= 1) vs += __shfl_xor(vs, m);
  const float rstd = rsqrtf(vs * (1.f / 768.f) + 1e-5f);
  const f32x4* gp = (const f32x4*)g;
  const f32x4* bp = (const f32x4*)b;
  bf16* orow = out + (size_t)row * CD;
#pragma unroll
  for (int i = 0; i < 3; ++i) {
    const int c4 = lane + 64 * i;
    f32x4 gg = gp[c4], bb = bp[c4];
    bf16x4 o;
#pragma unroll
    for (int j = 0; j < 4; ++j)
      o[j] = (bf16)((v[i][j] - mu) * rstd * gg[j] + bb[j]);
    *(bf16x4*)(orow + c4 * 4) = o;
  }
}

// ---------------------------------------------------------------------------
// FUSED: ys = xs + ao + cross(a1); write ys (f32) + ln1(ys),ln2(ys) (bf16)
// a1 is bf16 now.
// ---------------------------------------------------------------------------
__global__ __launch_bounds__(256) void fuse_res_ln(
    const float* __restrict__ x0, const float* __restrict__ x1,
    const float* __restrict__ x2, const float* __restrict__ x3,
    const float* __restrict__ x4, const float* __restrict__ add,
    const bf16* __restrict__ a, float* __restrict__ ys,
    const float* __restrict__ g1, const float* __restrict__ b1,
    const float* __restrict__ g2, const float* __restrict__ b2,
    bf16* __restrict__ o1, bf16* __restrict__ o2) {
  const int w = threadIdx.x >> 6, lane = threadIdx.x & 63;
  const int row = blockIdx.x * 4 + w;
  const int s = row >> 11, rem = row & 2047;
  const float* xp;
  switch (s) {
    case 0: xp = x0; break; case 1: xp = x1; break; case 2: xp = x2; break;
    case 3: xp = x3; break; default: xp = x4; break;
  }
  const f32x4* xr = (const f32x4*)(xp + (size_t)rem * CD);
  const f32x4* ar = (const f32x4*)(add + (size_t)row * CD);
  const bf16* am = a + (size_t)(row - 2048) * CD;
  const bf16* ap = a + (size_t)(row + 2048) * CD;
  f32x4 v[3];
#pragma unroll
  for (int i = 0; i < 3; ++i) {
    const int c4 = lane + 64 * i;
    f32x4 t = xr[c4] + ar[c4];
    if (s > 0) t += b4tof(am + c4 * 4);
    if (s < 4) t += b4tof(ap + c4 * 4);
    v[i] = t;
  }
  f32x4* yr = (f32x4*)(ys + (size_t)row * CD);
#pragma unroll
  for (int i = 0; i < 3; ++i) yr[lane + 64 * i] = v[i];

  float sum = 0.f;
#pragma unroll
  for (int i = 0; i < 3; ++i)
#pragma unroll
    for (int j = 0; j < 4; ++j) sum += v[i][j];
#pragma unroll
  for (int m = 32; m >= 1; m >>= 1) sum += __shfl_xor(sum, m);
  const float mu = sum * (1.f / 768.f);
  float vs = 0.f;
#pragma unroll
  for (int i = 0; i < 3; ++i)
#pragma unroll
    for (int j = 0; j < 4; ++j) { float d = v[i][j] - mu; vs += d * d; }
#pragma unroll
  for (int m = 32; m >= 1; m >>= 1) vs += __shfl_xor(vs, m);
  const float rstd = rsqrtf(vs * (1.f / 768.f) + 1e-5f);
  bf16* r1 = o1 + (size_t)row * CD;
  bf16* r2 = o2 + (size_t)row * CD;
#pragma unroll
  for (int i = 0; i < 3; ++i) {
    const int c4 = lane + 64 * i;
    f32x4 gg1 = ((const f32x4*)g1)[c4], bb1 = ((const f32x4*)b1)[c4];
    f32x4 gg2 = ((const f32x4*)g2)[c4], bb2 = ((const f32x4*)b2)[c4];
    bf16x4 oa, ob;
#pragma unroll
    for (int j = 0; j < 4; ++j) {
      float n = (v[i][j] - mu) * rstd;
      oa[j] = (bf16)(n * gg1[j] + bb1[j]);
      ob[j] = (bf16)(n * gg2[j] + bb2[j]);
    }
    *(bf16x4*)(r1 + c4 * 4) = oa;
    *(bf16x4*)(r2 + c4 * 4) = ob;
  }
}

// ---------------------------------------------------------------------------
// GEMM 256x256, BK=64, 8 waves (2M x 4N), 8-phase schedule (T2+T3+T4+T5).
// C[M,N] = A[M, ldk restricted to Klen window] @ Bt[N, same]^T + bias.
// Optional split-K: grid = nkp * nbm * nbn; kp = wg / bpk selects the K-half
// (A,Bt offset kp*Klen; output offset kp*kpstride elements; bias only kp==0).
// LDS double-buffered, k-chunk (16B) XOR-swizzled by (row&7) on BOTH global
// source (pre-swizzle) and ds_read. Counted vmcnt(4) at phases 4 and 8 only.
// EPI: 0 = f32 store, 1 = bf16 store, 2 = fast-GELU -> bf16 store
// ---------------------------------------------------------------------------
#define GBAR() __builtin_amdgcn_s_barrier()

#define LOADA(MH, BUF)                                                      \
  _Pragma("unroll") for (int m_ = 0; m_ < 4; ++m_) {                        \
    af[m_][0] =                                                             \
        *(const bf16x8*)&As[BUF][((MH)*128 + arow + m_ * 16) * 64 + ach0];  \
    af[m_][1] =                                                             \
        *(const bf16x8*)&As[BUF][((MH)*128 + arow + m_ * 16) * 64 + ach1];  \
  }

#define LOADB(DST, NH, BUF)                                                 \
  _Pragma("unroll") for (int n_ = 0; n_ < 2; ++n_) {                        \
    DST[n_][0] =                                                            \
        *(const bf16x8*)&Bs[BUF][(brow + (NH)*32 + n_ * 16) * 64 + ach0];   \
    DST[n_][1] =                                                            \
        *(const bf16x8*)&Bs[BUF][(brow + (NH)*32 + n_ * 16) * 64 + ach1];   \
  }

#define MFMA_PH(MH, NH, BF)                                                 \
  __builtin_amdgcn_s_setprio(1);                                            \
  _Pragma("unroll") for (int m_ = 0; m_ < 4; ++m_)                          \
  _Pragma("unroll") for (int n_ = 0; n_ < 2; ++n_) {                        \
    acc[(MH)*4 + m_][(NH)*2 + n_] =                                         \
        mfma16(af[m_][0], BF[n_][0], acc[(MH)*4 + m_][(NH)*2 + n_]);        \
    acc[(MH)*4 + m_][(NH)*2 + n_] =                                         \
        mfma16(af[m_][1], BF[n_][1], acc[(MH)*4 + m_][(NH)*2 + n_]);        \
  }                                                                         \
  __builtin_amdgcn_s_setprio(0);

template <int EPI>
__global__ __launch_bounds__(512, 2) void gemm256(
    const bf16* __restrict__ A, const bf16* __restrict__ Bt,
    const float* __restrict__ bias, void* __restrict__ Cout, int N, int Klen,
    int ldk, int nbn, int bpk, size_t kpstride) {
  __shared__ bf16 As[2][16384];
  __shared__ bf16 Bs[2][16384];
  const int t = threadIdx.x, lane = t & 63, w = t >> 6;
  const int wm = w >> 2, wn = w & 3;

  // bijective XCD-chunked remap (gridDim.x % 8 == 0 by construction)
  const int chunkg = gridDim.x >> 3;
  const int wg = (blockIdx.x & 7) * chunkg + (blockIdx.x >> 3);
  const int kp = wg / bpk, rem = wg % bpk;
  const int bm = rem / nbn, bn = rem % nbn;

  f32x4 acc[8][4] = {};

  const int srow = t >> 3;
  const int scol = ((t & 7) ^ (srow & 7)) << 3;
  const size_t koff = (size_t)kp * Klen;
  const bf16* Ab = A + (size_t)(bm * 256 + srow) * ldk + koff + scol;
  const bf16* Bb = Bt + (size_t)(bn * 256 + srow) * ldk + koff + scol;
  const size_t r64 = (size_t)64 * ldk;

  auto stage_a = [&](int buf, int h, int kt) {
    const bf16* g = Ab + (size_t)h * 128 * ldk + (size_t)kt * 64;
    gload16(g, &As[buf][h * 8192 + w * 512]);
    gload16(g + r64, &As[buf][h * 8192 + 4096 + w * 512]);
  };
  auto stage_b = [&](int buf, int h, int kt) {
    const bf16* g = Bb + (size_t)h * 128 * ldk + (size_t)kt * 64;
    gload16(g, &Bs[buf][h * 8192 + w * 512]);
    gload16(g + r64, &Bs[buf][h * 8192 + 4096 + w * 512]);
  };

  const int arow = wm * 64 + (lane & 15);
  const int brow = wn * 64 + (lane & 15);
  const int ach0 = (((lane >> 4) + 0) ^ (lane & 7)) << 3;
  const int ach1 = (((lane >> 4) + 4) ^ (lane & 7)) << 3;

  // prologue: T0 {A0,B0,B1,A1}, T1 {A0,B0}
  stage_a(0, 0, 0); stage_b(0, 0, 0); stage_b(0, 1, 0); stage_a(0, 1, 0);
  stage_a(1, 0, 1); stage_b(1, 0, 1);
  asm volatile("s_waitcnt vmcnt(4)" ::: "memory");  // T0 landed
  GBAR();

  const int NT = Klen >> 6, NI = NT >> 1;
  bf16x8 af[4][2], bf0[2][2], bf1[2][2];

  for (int j = 0; j < NI; ++j) {
    const int tA = 2 * j, tB = 2 * j + 1;
    const bool notlast = (j + 1 < NI);

    // ======== tile tA from buf 0 ========
    LOADA(0, 0);
    LOADB(bf0, 0, 0);
    stage_b(1, 1, tB);
    GBAR();
    MFMA_PH(0, 0, bf0);
    GBAR();
    LOADB(bf1, 1, 0);
    stage_a(1, 1, tB);
    GBAR();
    MFMA_PH(0, 1, bf1);
    GBAR();
    LOADA(1, 0);
    if (notlast) stage_a(0, 0, tA + 2);
    GBAR();
    MFMA_PH(1, 0, bf0);
    GBAR();
    if (notlast) {
      stage_b(0, 0, tA + 2);
      asm volatile("s_waitcnt vmcnt(4)" ::: "memory");
    } else {
      asm volatile("s_waitcnt vmcnt(0)" ::: "memory");
    }
    GBAR();
    MFMA_PH(1, 1, bf1);
    GBAR();

    // ======== tile tB from buf 1 ========
    LOADA(0, 1);
    LOADB(bf0, 0, 1);
    if (notlast) stage_b(0, 1, tA + 2);
    GBAR();
    MFMA_PH(0, 0, bf0);
    GBAR();
    LOADB(bf1, 1, 1);
    if (notlast) stage_a(0, 1, tA + 2);
    GBAR();
    MFMA_PH(0, 1, bf1);
    GBAR();
    LOADA(1, 1);
    if (notlast) stage_a(1, 0, tB + 2);
    GBAR();
    MFMA_PH(1, 0, bf0);
    GBAR();
    if (notlast) {
      stage_b(1, 0, tB + 2);
      asm volatile("s_waitcnt vmcnt(4)" ::: "memory");
    }
    GBAR();
    MFMA_PH(1, 1, bf1);
    GBAR();
  }

  // epilogue (bias only on kp==0 so split-K partials sum correctly)
#pragma unroll
  for (int am = 0; am < 8; ++am) {
    const int grow0 =
        bm * 256 + (am >> 2) * 128 + wm * 64 + (am & 3) * 16 + (lane >> 4) * 4;
#pragma unroll
    for (int an = 0; an < 4; ++an) {
      const int gcol = bn * 256 + wn * 64 + an * 16 + (lane & 15);
      const float bv = (kp == 0) ? bias[gcol] : 0.f;
#pragma unroll
      for (int r = 0; r < 4; ++r) {
        float v = acc[am][an][r] + bv;
        if (EPI == 2) v = fast_gelu(v);
        const size_t idx = (size_t)(grow0 + r) * N + gcol + kp * kpstride;
        if (EPI == 0) ((float*)Cout)[idx] = v;
        else ((bf16*)Cout)[idx] = (bf16)v;
      }
    }
  }
}

// ---------------------------------------------------------------------------
// Flash attention v2 — swapped-operand 32x32 MFMA, in-register softmax.
// ---------------------------------------------------------------------------
__global__ __launch_bounds__(256, 3) void attn_v2(
    const bf16* __restrict__ qkv, bf16* __restrict__ obuf) {
  __shared__ bf16 Ks[2][4096];
  __shared__ bf16 Vt[2][4096];
  const int t = threadIdx.x, lane = t & 63, w = t >> 6;
  const int g = lane >> 5, q32 = lane & 31, rq7 = q32 & 7;

  const int xcd = blockIdx.x & 7, slot = blockIdx.x >> 3;
  const int work = xcd * 120 + slot;
  const int sbh = work >> 3, qt = work & 7;
  const int sb = sbh / NH, h = sbh % NH;
  const size_t tokbase = (size_t)sb * SEQ;
  const int qoff = h * 64, koff = CD + h * 64, voff = 2 * CD + h * 64;

  const int qrow = qt * 128 + w * 32 + q32;
  bf16x8 qf[4];
  {
    const bf16* qp = qkv + (tokbase + qrow) * NQKV + qoff + g * 8;
#pragma unroll
    for (int kd = 0; kd < 4; ++kd) {
      bf16x8 v = *(const bf16x8*)(qp + kd * 16);
#pragma unroll
      for (int j = 0; j < 8; ++j) v[j] = (bf16)((float)v[j] * 0.125f);
      qf[kd] = v;
    }
  }

  const int skv1 = t >> 3, sc1 = (t & 7) ^ (skv1 & 7);
  const int skv2 = (t + 256) >> 3, sc2 = (t & 7) ^ (skv2 & 7);
  const int vkv0 = 2 * (t & 31);
  const int vd0 = 8 * (t >> 5);
  const int c0 = (vkv0 & 51) | ((vkv0 & 4) << 1) | ((vkv0 & 8) >> 1);
  const int vchunk = c0 >> 3, vsub = c0 & 7;
  const bf16* kbase = qkv + tokbase * NQKV + koff;
  const bf16* vbase = qkv + tokbase * NQKV + voff;

  {
    const bf16* kb0 = kbase;
    gload16(kb0 + (size_t)skv1 * NQKV + sc1 * 8, &Ks[0][w * 512]);
    gload16(kb0 + (size_t)skv2 * NQKV + sc2 * 8, &Ks[0][2048 + w * 512]);
    const bf16* vp = vbase + (size_t)vkv0 * NQKV + vd0;
    bf16x8 r0 = *(const bf16x8*)vp;
    bf16x8 r1 = *(const bf16x8*)(vp + NQKV);
#pragma unroll
    for (int j = 0; j < 8; ++j) {
      const int d = vd0 + j;
      *(unsigned*)&Vt[0][d * 64 + ((vchunk ^ j) << 3) + vsub] =
          pack2(r0[j], r1[j]);
    }
  }
  __syncthreads();

  float m_run = -1e30f, l_run = 0.f;
  f32x16 oT0 = {}, oT1 = {};
  int cur = 0;

  for (int kt = 0; kt < 16; ++kt) {
    bf16x8 nv0, nv1;
    if (kt < 15) {
      const bf16* vp = vbase + (size_t)((kt + 1) * 64 + vkv0) * NQKV + vd0;
      nv0 = *(const bf16x8*)vp;
      nv1 = *(const bf16x8*)(vp + NQKV);
      const bf16* kb0 = kbase + (size_t)(kt + 1) * 64 * NQKV;
      gload16(kb0 + (size_t)skv1 * NQKV + sc1 * 8, &Ks[cur ^ 1][w * 512]);
      gload16(kb0 + (size_t)skv2 * NQKV + sc2 * 8,
              &Ks[cur ^ 1][2048 + w * 512]);
    }

    f32x16 sT0 = {}, sT1 = {};
#pragma unroll
    for (int kd = 0; kd < 4; ++kd) {
      bf16x8 kf0 =
          *(const bf16x8*)&Ks[cur][q32 * 64 + (((2 * kd + g) ^ rq7) << 3)];
      bf16x8 kf1 = *(const bf16x8*)&Ks[cur][(32 + q32) * 64 +
                                            (((2 * kd + g) ^ rq7) << 3)];
      sT0 = mfma32(kf0, qf[kd], sT0);
      sT1 = mfma32(kf1, qf[kd], sT1);
    }

    float mt = sT0[0];
#pragma unroll
    for (int r = 1; r < 16; ++r) mt = fmaxf(mt, sT0[r]);
#pragma unroll
    for (int r = 0; r < 16; ++r) mt = fmaxf(mt, sT1[r]);
    mt = fmaxf(mt, __shfl_xor(mt, 32));
    const float mnew = fmaxf(m_run, mt);
    const float alpha = __expf(m_run - mnew);
    m_run = mnew;
    float rs = 0.f;
#pragma unroll
    for (int r = 0; r < 16; ++r) {
      sT0[r] = __expf(sT0[r] - mnew);
      rs += sT0[r];
    }
#pragma unroll
    for (int r = 0; r < 16; ++r) {
      sT1[r] = __expf(sT1[r] - mnew);
      rs += sT1[r];
    }
    rs += __shfl_xor(rs, 32);
    l_run = l_run * alpha + rs;
#pragma unroll
    for (int r = 0; r < 16; ++r) { oT0[r] *= alpha; oT1[r] *= alpha; }

    bf16x8 pa[4];
#pragma unroll
    for (int hh = 0; hh < 2; ++hh)
#pragma unroll
      for (int j = 0; j < 8; ++j) {
        pa[hh][j] = (bf16)sT0[8 * hh + j];
        pa[2 + hh][j] = (bf16)sT1[8 * hh + j];
      }

#pragma unroll
    for (int ks = 0; ks < 4; ++ks) {
      bf16x8 vf0 =
          *(const bf16x8*)&Vt[cur][q32 * 64 + (((2 * ks + g) ^ rq7) << 3)];
      bf16x8 vf1 = *(const bf16x8*)&Vt[cur][(32 + q32) * 64 +
                                            (((2 * ks + g) ^ rq7) << 3)];
      oT0 = mfma32(vf0, pa[ks], oT0);
      oT1 = mfma32(vf1, pa[ks], oT1);
    }

    if (kt < 15) {
#pragma unroll
      for (int j = 0; j < 8; ++j) {
        const int d = vd0 + j;
        *(unsigned*)&Vt[cur ^ 1][d * 64 + ((vchunk ^ j) << 3) + vsub] =
            pack2(nv0[j], nv1[j]);
      }
    }
    __syncthreads();
    cur ^= 1;
  }

  const float rl = 1.f / l_run;
  bf16* orow = obuf + (tokbase + qrow) * CD + h * 64;
#pragma unroll
  for (int m = 0; m < 4; ++m) {
    bf16x4 o0, o1;
#pragma unroll
    for (int r = 0; r < 4; ++r) {
      o0[r] = (bf16)(oT0[4 * m + r] * rl);
      o1[r] = (bf16)(oT1[4 * m + r] * rl);
    }
    *(bf16x4*)(orow + 8 * m + 4 * g) = o0;
    *(bf16x4*)(orow + 32 + 8 * m + 4 * g) = o1;
  }
}

// ---------------------------------------------------------------------------
// Adapter: out = ((X@dw+db)@mw+mb)@uw+ub ; X bf16 [TOK][768], out bf16.
// ---------------------------------------------------------------------------
__global__ __launch_bounds__(256) void adapter_kernel(
    const bf16* __restrict__ X, const float* __restrict__ dw,
    const float* __restrict__ db, const float* __restrict__ mw,
    const float* __restrict__ mb, const float* __restrict__ uw,
    const float* __restrict__ ub, bf16* __restrict__ out) {
  const int tok = blockIdx.x * 4 + (threadIdx.x >> 6);
  const int lane = threadIdx.x & 63;
  const bf16* xr = X + (size_t)tok * CD;
  float xv[12];
#pragma unroll
  for (int i = 0; i < 12; ++i) xv[i] = (float)xr[lane + 64 * i];
  float h1[8] = {0, 0, 0, 0, 0, 0, 0, 0};
#pragma unroll
  for (int i = 0; i < 12; ++i) {
    const f32x4* dr = (const f32x4*)(dw + (size_t)(lane + 64 * i) * 8);
    f32x4 d0 = dr[0], d1 = dr[1];
#pragma unroll
    for (int j = 0; j < 4; ++j) {
      h1[j] += xv[i] * d0[j];
      h1[4 + j] += xv[i] * d1[j];
    }
  }
#pragma unroll
  for (int m = 1; m < 64; m <<= 1)
#pragma unroll
    for (int j = 0; j < 8; ++j) h1[j] += __shfl_xor(h1[j], m);
#pragma unroll
  for (int j = 0; j < 8; ++j) h1[j] += db[j];
  float h2[8];
#pragma unroll
  for (int k = 0; k < 8; ++k) {
    float v = mb[k];
#pragma unroll
    for (int j = 0; j < 8; ++j) v += h1[j] * mw[j * 8 + k];
    h2[k] = v;
  }
#pragma unroll
  for (int i = 0; i < 12; ++i) {
    const int c = lane + 64 * i;
    float v = ub[c];
#pragma unroll
    for (int k = 0; k < 8; ++k) v += h2[k] * uw[k * CD + c];
    out[(size_t)tok * CD + c] = (bf16)v;
  }
}

// ---------------------------------------------------------------------------
// Final: z[s] = ys[s] + m0[s] + m1[s] + (s>0 ? a[s-1] : 0) + (s<4 ? a[s+1] : 0)
// m0/m1 = split-K bf16 partials (stacked at +TOK*CD); a = a2 bf16.
// ---------------------------------------------------------------------------
__global__ __launch_bounds__(256) void cross_residual(
    const float* __restrict__ ys, const bf16* __restrict__ m01,
    const bf16* __restrict__ a, float* __restrict__ out) {
  const int s = blockIdx.y;
  const size_t i = (size_t)blockIdx.x * 256 + threadIdx.x;  // group-of-4 index
  const size_t spitch = (size_t)2048 * 768 / 4;
  const size_t sb = (size_t)s * spitch;
  const size_t mstride = (size_t)TOK * CD / 4;
  f32x4 v = ((const f32x4*)ys)[sb + i];
  v += b4tof(m01 + (sb + i) * 4);
  v += b4tof(m01 + (mstride + sb + i) * 4);
  if (s > 0) v += b4tof(a + (sb - spitch + i) * 4);
  if (s < 4) v += b4tof(a + (sb + spitch + i) * 4);
  ((f32x4*)out)[sb + i] = v;
}

// ---------------------------------------------------------------------------
// workspace layout (bytes; ~203 MB)
// ---------------------------------------------------------------------------
#define OFF_WTQKV  ((size_t)0)           // bf16 [2304][768]
#define OFF_WTPROJ ((size_t)3538944)     // bf16 [768][768]
#define OFF_WTFC1  ((size_t)4718592)     // bf16 [3072][768]
#define OFF_WTFC2  ((size_t)9437184)     // bf16 [768][3072]
#define OFF_N1     ((size_t)14155776)    // bf16 [10240][768]; later ln1(ys)
#define OFF_BIG    ((size_t)29884416)    // bf16 qkv [10240][2304]; later h [10240][3072]
#define OFF_OBUF   ((size_t)77070336)    // bf16 o [10240][768] (tail of BIG)
#define OFF_AOM    ((size_t)92798976)    // f32 ao [10240][768]; later bf16 m0,m1 stacked
#define OFF_A12    ((size_t)124256256)   // bf16 [10240][768]: a1, later a2
#define OFF_YS     ((size_t)155713536)   // f32 [10240][768]
#define OFF_L2Y    ((size_t)187170816)   // bf16 [10240][768]

extern "C" void kernel_launch(void* const* d_in, const int* in_sizes, int n_in,
                              void* d_out, int out_size, void* d_ws,
                              size_t ws_size, hipStream_t stream) {
  const float* x0 = (const float*)d_in[0];
  const float* x1 = (const float*)d_in[1];
  const float* x2 = (const float*)d_in[2];
  const float* x3 = (const float*)d_in[3];
  const float* x4 = (const float*)d_in[4];
  const float* ln1_g = (const float*)d_in[5];
  const float* ln1_b = (const float*)d_in[6];
  const float* ln2_g = (const float*)d_in[7];
  const float* ln2_b = (const float*)d_in[8];
  const float* qkv_w = (const float*)d_in[9];
  const float* qkv_b = (const float*)d_in[10];
  const float* proj_w = (const float*)d_in[11];
  const float* proj_b = (const float*)d_in[12];
  const float* fc1_w = (const float*)d_in[13];
  const float* fc1_b = (const float*)d_in[14];
  const float* fc2_w = (const float*)d_in[15];
  const float* fc2_b = (const float*)d_in[16];
  const float* at_dw = (const float*)d_in[17];
  const float* at_db = (const float*)d_in[18];
  const float* at_mw = (const float*)d_in[19];
  const float* at_mb = (const float*)d_in[20];
  const float* at_uw = (const float*)d_in[21];
  const float* at_ub = (const float*)d_in[22];
  const float* a2_dw = (const float*)d_in[23];
  const float* a2_db = (const float*)d_in[24];
  const float* a2_mw = (const float*)d_in[25];
  const float* a2_mb = (const float*)d_in[26];
  const float* a2_uw = (const float*)d_in[27];
  const float* a2_ub = (const float*)d_in[28];

  char* ws = (char*)d_ws;
  bf16* wt_qkv = (bf16*)(ws + OFF_WTQKV);
  bf16* wt_proj = (bf16*)(ws + OFF_WTPROJ);
  bf16* wt_fc1 = (bf16*)(ws + OFF_WTFC1);
  bf16* wt_fc2 = (bf16*)(ws + OFF_WTFC2);
  bf16* n1 = (bf16*)(ws + OFF_N1);
  bf16* qkvb = (bf16*)(ws + OFF_BIG);
  bf16* obuf = (bf16*)(ws + OFF_OBUF);
  float* aof = (float*)(ws + OFF_AOM);   // proj out (f32)
  bf16* mbuf = (bf16*)(ws + OFF_AOM);    // fc2 split partials m0,m1 (bf16 x2)
  bf16* a12 = (bf16*)(ws + OFF_A12);
  float* ysb = (float*)(ws + OFF_YS);
  bf16* l2y = (bf16*)(ws + OFF_L2Y);

  const dim3 b256(256);
  const dim3 b512(512);

  // 1. weight convert+transpose -> bf16 [N][K]
  transpose_to_bf16<<<dim3(72, 24), b256, 0, stream>>>(qkv_w, wt_qkv, 768, 2304);
  transpose_to_bf16<<<dim3(24, 24), b256, 0, stream>>>(proj_w, wt_proj, 768, 768);
  transpose_to_bf16<<<dim3(96, 24), b256, 0, stream>>>(fc1_w, wt_fc1, 768, 3072);
  transpose_to_bf16<<<dim3(24, 96), b256, 0, stream>>>(fc2_w, wt_fc2, 3072, 768);

  // 2. n1 = LN(xs)  (bf16)
  ln5_kernel<<<2560, b256, 0, stream>>>(x0, x1, x2, x3, x4, ln1_g, ln1_b, n1);

  // 3. qkv = n1 @ qkv_w + qkv_b  (bf16)   grid 40*9=360
  gemm256<1><<<360, b512, 0, stream>>>(n1, wt_qkv, qkv_b, qkvb, NQKV, 768, 768,
                                       9, 360, 0);

  // 4. a1 = adapter(n1)  (bf16)
  adapter_kernel<<<2560, b256, 0, stream>>>(n1, at_dw, at_db, at_mw, at_mb,
                                            at_uw, at_ub, a12);

  // 5. attention -> o (bf16)
  attn_v2<<<960, b256, 0, stream>>>(qkvb, obuf);

  // 6. ao = o @ proj_w + proj_b  (f32)   grid 40*3=120
  gemm256<0><<<120, b512, 0, stream>>>(obuf, wt_proj, proj_b, aof, CD, 768,
                                       768, 3, 120, 0);

  // 7+8. ys = xs + ao + cross(a1); ln1(ys)->n1, ln2(ys)->l2y  (fused)
  fuse_res_ln<<<2560, b256, 0, stream>>>(x0, x1, x2, x3, x4, aof, a12, ysb,
                                         ln1_g, ln1_b, ln2_g, ln2_b, n1, l2y);

  // 9. a2 = adapter(ln1(ys))  (bf16, overwrites a1)
  adapter_kernel<<<2560, b256, 0, stream>>>(n1, a2_dw, a2_db, a2_mw, a2_mb,
                                            a2_uw, a2_ub, a12);

  // 10. h = gelu(ln2(ys) @ fc1_w + fc1_b)  (bf16)   grid 40*12=480
  gemm256<2><<<480, b512, 0, stream>>>(l2y, wt_fc1, fc1_b, qkvb, NHID, 768,
                                       768, 12, 480, 0);

  // 11. m = h @ fc2_w + fc2_b  — split-K=2, bf16 partials m0,m1
  //     grid 2*40*3=240; kp selects K-half (Klen=1536 of ldk=3072)
  gemm256<1><<<240, b512, 0, stream>>>(qkvb, wt_fc2, fc2_b, mbuf, CD, 1536,
                                       3072, 3, 120, (size_t)TOK * CD);

  // 12. z = ys + (m0+m1) + cross(a2) -> d_out
  cross_residual<<<dim3(1536, 5), b256, 0, stream>>>(ysb, mbuf, a12,
                                                     (float*)d_out);
}